// Round 1
// baseline (1131.783 us; speedup 1.0000x reference)
//
#include <hip/hip_runtime.h>
#include <math.h>

// instant-NGP style fused kernel: hash-grid encode (16 levels) + sigma MLP +
// color MLP, one point per thread. fp32 throughout (matches reference; no
// fp32 MFMA on CDNA4 so first cut is vector-ALU).
//
// NOTE: reference has a bug we must replicate: final trilerp uses
//   c0*(1-fz) + c1*fy        (fy, not fz!)

#define BLOCK 256

__global__ __launch_bounds__(BLOCK)
void nerf_fused(const float* __restrict__ x,
                const float* __restrict__ grids,
                const float* __restrict__ w1,   // (32,64)
                const float* __restrict__ w2,   // (64,16)
                const float* __restrict__ wc1,  // (32,64)
                const float* __restrict__ wc2,  // (64,64)
                const float* __restrict__ wc3,  // (64,3)
                float* __restrict__ out,        // (N,4)
                int n)
{
    // levels: res and table sizes, exactly as the Python _levels() computes.
    // MAX_DIRECT = 2 (levels 0..2 direct-indexed, 3+ hashed).
    constexpr int   NL[16] = {16,22,28,37,49,65,85,112,148,195,257,338,446,589,777,1025};
    constexpr unsigned SZ[16] = {4096u,10648u,21952u,50656u,117656u,274632u,
                                 524288u,524288u,524288u,524288u,524288u,
                                 524288u,524288u,524288u,524288u,524288u};
    constexpr unsigned H2 = 2654435761u, H3 = 805459861u;
    constexpr int TSTRIDE = 524288 * 2;  // floats per level row of grids

    __shared__ float s_x[BLOCK * 19];

    const int t = threadIdx.x;
    const int base = blockIdx.x * BLOCK;

    // coalesced stage of x rows (19 floats/row) into LDS
    {
        const float* xb = x + (size_t)base * 19;
        int limit = (n - base) * 19;
        if (limit > BLOCK * 19) limit = BLOCK * 19;
        #pragma unroll
        for (int i = 0; i < 19; ++i) {
            int g = i * BLOCK + t;
            if (g < limit) s_x[g] = xb[g];
        }
    }
    __syncthreads();

    const int pid = base + t;
    if (pid >= n) return;

    const float px = s_x[t*19+0];
    const float py = s_x[t*19+1];
    const float pz = s_x[t*19+2];

    // ---------------- hash-grid encode ----------------
    float enc[32];
    #pragma unroll
    for (int l = 0; l < 16; ++l) {
        const float Rf = (float)NL[l];
        float ux = px*Rf, uy = py*Rf, uz = pz*Rf;
        float gx = floorf(ux), gy = floorf(uy), gz = floorf(uz);
        float fx = ux-gx, fy = uy-gy, fz = uz-gz;
        int ix = (int)gx, iy = (int)gy, iz = (int)gz;
        const float2* gl = (const float2*)(grids + (size_t)l * TSTRIDE);

        float f0[8], f1[8];
        #pragma unroll
        for (int j = 0; j < 8; ++j) {
            int ox = ix + ((j>>2)&1);
            int oy = iy + ((j>>1)&1);
            int oz = iz + (j&1);
            unsigned idx;
            if (l <= 2) {
                int R = NL[l];
                idx = (unsigned)((oz*(R*R) + oy*R + ox) % (int)SZ[l]);
            } else {
                unsigned h = (unsigned)ox * 1u
                           ^ (unsigned)oy * H2
                           ^ (unsigned)oz * H3;
                idx = h % SZ[l];
            }
            float2 v = gl[idx];
            f0[j] = v.x; f1[j] = v.y;
        }
        const float w0x = 1.f-fx, w0y = 1.f-fy, w0z = 1.f-fz;
        {
            float c00 = f0[0]*w0x + f0[4]*fx;
            float c01 = f0[1]*w0x + f0[5]*fx;
            float c10 = f0[2]*w0x + f0[6]*fx;
            float c11 = f0[3]*w0x + f0[7]*fx;
            float c0 = c00*w0y + c10*fy;
            float c1 = c01*w0y + c11*fy;
            enc[2*l+0] = c0*w0z + c1*fy;   // reference bug: fy (not fz)
        }
        {
            float c00 = f1[0]*w0x + f1[4]*fx;
            float c01 = f1[1]*w0x + f1[5]*fx;
            float c10 = f1[2]*w0x + f1[6]*fx;
            float c11 = f1[3]*w0x + f1[7]*fx;
            float c0 = c00*w0y + c10*fy;
            float c1 = c01*w0y + c11*fy;
            enc[2*l+1] = c0*w0z + c1*fy;   // reference bug: fy (not fz)
        }
    }

    // ---------------- sigma MLP: h = relu(enc @ w1); o = h @ w2 ----------------
    float h[64];
    #pragma unroll
    for (int j = 0; j < 64; ++j) h[j] = 0.f;
    for (int k = 0; k < 32; ++k) {          // weights uniform -> s_load
        float a = enc[k];
        const float* wr = w1 + k*64;
        #pragma unroll
        for (int j = 0; j < 64; ++j) h[j] = fmaf(a, wr[j], h[j]);
    }
    #pragma unroll
    for (int j = 0; j < 64; ++j) h[j] = fmaxf(h[j], 0.f);

    float o[16];
    #pragma unroll
    for (int j = 0; j < 16; ++j) o[j] = 0.f;
    for (int k = 0; k < 64; ++k) {
        float a = h[k];
        const float* wr = w2 + k*16;
        #pragma unroll
        for (int j = 0; j < 16; ++j) o[j] = fmaf(a, wr[j], o[j]);
    }
    const float sigma = o[0];

    // ---------------- color MLP ----------------
    // hc = relu(ci @ wc1), ci = [direc(16), o(16)]
    float hc[64];
    #pragma unroll
    for (int j = 0; j < 64; ++j) hc[j] = 0.f;
    for (int k = 0; k < 16; ++k) {
        float a = s_x[t*19 + 3 + k];
        const float* wr = wc1 + k*64;
        #pragma unroll
        for (int j = 0; j < 64; ++j) hc[j] = fmaf(a, wr[j], hc[j]);
    }
    for (int k = 0; k < 16; ++k) {
        float a = o[k];
        const float* wr = wc1 + (16+k)*64;
        #pragma unroll
        for (int j = 0; j < 64; ++j) hc[j] = fmaf(a, wr[j], hc[j]);
    }
    #pragma unroll
    for (int j = 0; j < 64; ++j) hc[j] = fmaxf(hc[j], 0.f);

    // hc2 = relu(hc @ wc2) folded straight into color accumulators, in two
    // 32-wide halves to cap register pressure.
    float col0 = 0.f, col1 = 0.f, col2 = 0.f;
    #pragma unroll
    for (int half = 0; half < 2; ++half) {
        float h2[32];
        #pragma unroll
        for (int j = 0; j < 32; ++j) h2[j] = 0.f;
        for (int k = 0; k < 64; ++k) {
            float a = hc[k];
            const float* wr = wc2 + k*64 + half*32;
            #pragma unroll
            for (int j = 0; j < 32; ++j) h2[j] = fmaf(a, wr[j], h2[j]);
        }
        const float* w3 = wc3 + half*32*3;
        #pragma unroll
        for (int j = 0; j < 32; ++j) {
            float v = fmaxf(h2[j], 0.f);
            col0 = fmaf(v, w3[j*3+0], col0);
            col1 = fmaf(v, w3[j*3+1], col1);
            col2 = fmaf(v, w3[j*3+2], col2);
        }
    }

    float4 res;
    res.x = 1.f / (1.f + __expf(-col0));
    res.y = 1.f / (1.f + __expf(-col1));
    res.z = 1.f / (1.f + __expf(-col2));
    res.w = sigma;
    ((float4*)out)[pid] = res;
}

extern "C" void kernel_launch(void* const* d_in, const int* in_sizes, int n_in,
                              void* d_out, int out_size, void* d_ws, size_t ws_size,
                              hipStream_t stream) {
    const float* x     = (const float*)d_in[0];
    const float* grids = (const float*)d_in[1];
    const float* w1    = (const float*)d_in[2];
    const float* w2    = (const float*)d_in[3];
    const float* wc1   = (const float*)d_in[4];
    const float* wc2   = (const float*)d_in[5];
    const float* wc3   = (const float*)d_in[6];
    float* out = (float*)d_out;

    int n = in_sizes[0] / 19;
    int grid = (n + BLOCK - 1) / BLOCK;
    nerf_fused<<<grid, BLOCK, 0, stream>>>(x, grids, w1, w2, wc1, wc2, wc3, out, n);
}